// Round 16
// baseline (166.596 us; speedup 1.0000x reference)
//
#include <hip/hip_runtime.h>
#include <cstdint>

#define N_NODES 50000
#define N_EDGES 1600000
#define NPAD 50048                    // 782 tiles * 64
#define NTILES (NPAD / 64)            // 782
#define DUMMY 50000                   // zero row in padded tables

#define NCOARSE 196                   // ceil(50000/256)
#define CBLK 256                      // blocks in coarse pass
#define ECHUNK (N_EDGES / CBLK)       // 6250 edges per block

#define ONW 12500                     // 50000 nodes as u8-packed u32 words
#define OPARTS 256
#define OCH (N_EDGES / OPARTS)        // 6250 edges per part

#define AGG_BPP 3125                  // agg blocks per phase (16 nodes/block)

typedef __attribute__((ext_vector_type(8))) _Float16 f16x8;
typedef __attribute__((ext_vector_type(2))) _Float16 f16x2;
typedef __attribute__((ext_vector_type(4))) float f32x4;

// ---------------- helpers ----------------
__device__ __forceinline__ unsigned f16rn(float f) {
    _Float16 h = (_Float16)f;
    return (unsigned)__builtin_bit_cast(unsigned short, h);
}
__device__ __forceinline__ f16x2 u2h(unsigned u) { return __builtin_bit_cast(f16x2, u); }
__device__ __forceinline__ f16x2 pk_xor_add(f16x2 s, int d) {
    unsigned u = __builtin_bit_cast(unsigned, s);
    unsigned o = (unsigned)__shfl_xor((int)u, d);
    return s + __builtin_bit_cast(f16x2, o);           // v_pk_add_f16
}

// ---- F1: odp u8 (blocks 0..255) || hist (256..511) || wprep (512..543) ----
__global__ void k_fuse1(const int* __restrict__ src, const int* __restrict__ dst,
                        const float* __restrict__ W1, const float* __restrict__ W2,
                        unsigned* __restrict__ counts, unsigned* __restrict__ partial,
                        unsigned* __restrict__ Wt1, unsigned* __restrict__ Wt2) {
    __shared__ unsigned sm[ONW];      // 50 KB
    int b = blockIdx.x, tid = threadIdx.x;
    if (b < 256) {
        // outdeg partial histograms, 4x u8 packed per u32
        for (int i = tid; i < ONW; i += 256) sm[i] = 0;
        __syncthreads();
        int ebase = b * OCH;
        for (int i = tid; i < OCH; i += 256) {
            int sv = src[ebase + i];
            atomicAdd(&sm[sv >> 2], 1u << ((sv & 3) * 8));
        }
        __syncthreads();
        unsigned* outp = partial + (size_t)b * ONW;
        for (int i = tid; i < ONW; i += 256) outp[i] = sm[i];
    } else if (b < 512) {
        // coarse dst histogram
        int b2 = b - 256;
        for (int i = tid; i < NCOARSE; i += 256) sm[i] = 0;
        __syncthreads();
        int base = b2 * ECHUNK;
        for (int i = tid; i < ECHUNK; i += 256)
            atomicAdd(&sm[(unsigned)dst[base + i] >> 8], 1u);
        __syncthreads();
        for (int i = tid; i < NCOARSE; i += 256)
            counts[b2 * NCOARSE + i] = sm[i];
    } else {
        // W prep: Wt[n][kp] = packed fp16 (W[2kp][n], W[2kp+1][n])
        int t = (b - 512) * 256 + tid;
        if (t < 128 * 64) {
            int n = t >> 6, kp = t & 63;
            Wt1[t] = f16rn(W1[(2 * kp) * 128 + n]) | (f16rn(W1[(2 * kp + 1) * 128 + n]) << 16);
        }
        if (t < 64 * 64) {
            int n = t >> 6, kp = t & 63;
            Wt2[t] = f16rn(W2[(2 * kp) * 64 + n]) | (f16rn(W2[(2 * kp + 1) * 64 + n]) << 16);
        }
    }
}

// ---- scanA: scan block-counts within each coarse bucket ----
__global__ void k_scanA(const unsigned* __restrict__ counts, unsigned* __restrict__ woff,
                        unsigned* __restrict__ tot) {
    __shared__ unsigned s[256];
    int c = blockIdx.x, t = threadIdx.x;
    unsigned v = counts[t * NCOARSE + c];
    s[t] = v; __syncthreads();
    for (int o = 1; o < 256; o <<= 1) {
        unsigned u = (t >= o) ? s[t - o] : 0u;
        __syncthreads(); s[t] += u; __syncthreads();
    }
    woff[t * NCOARSE + c] = s[t] - v;
    if (t == 255) tot[c] = s[255];
}

// ---- scanB: scan bucket totals -> base[], row_ptr tail ----
__global__ void k_scanB(const unsigned* __restrict__ tot, unsigned* __restrict__ base,
                        unsigned* __restrict__ row_ptr) {
    __shared__ unsigned s[256];
    int t = threadIdx.x;
    unsigned v = (t < NCOARSE) ? tot[t] : 0u;
    s[t] = v; __syncthreads();
    for (int o = 1; o < 256; o <<= 1) {
        unsigned u = (t >= o) ? s[t - o] : 0u;
        __syncthreads(); s[t] += u; __syncthreads();
    }
    if (t < NCOARSE) base[t] = s[t] - v;
    if (t == NCOARSE - 1) base[NCOARSE] = s[t];   // == N_EDGES
    if (t == 0) row_ptr[N_NODES] = N_EDGES;
}

// ---- F2: scat1 (blocks 0..255) || on-reduce (256..304) ----
__global__ void k_fuse2(const int* __restrict__ src, const int* __restrict__ dst,
                        const unsigned* __restrict__ base, const unsigned* __restrict__ woff,
                        int* __restrict__ tmp_s, int* __restrict__ tmp_d,
                        const unsigned* __restrict__ partial, float* __restrict__ on) {
    __shared__ unsigned cur[NCOARSE];
    int b = blockIdx.x, t = threadIdx.x;
    if (b < 256) {
        for (int i = t; i < NCOARSE; i += 256) cur[i] = base[i] + woff[b * NCOARSE + i];
        __syncthreads();
        int ebase = b * ECHUNK;
        for (int i = t; i < ECHUNK; i += 256) {
            int d = dst[ebase + i], sv = src[ebase + i];
            unsigned p = atomicAdd(&cur[(unsigned)d >> 8], 1u);
            tmp_d[p] = d; tmp_s[p] = sv;
        }
    } else {
        int tt = (b - 256) * 256 + t;   // packed word index
        if (tt < ONW) {
            const unsigned* p = partial + tt;
            unsigned a0 = 0, a1 = 0, a2 = 0, a3 = 0;
            for (int q = 0; q < OPARTS; ++q) {
                unsigned v = p[(size_t)q * ONW];
                a0 += v & 255u; a1 += (v >> 8) & 255u;
                a2 += (v >> 16) & 255u; a3 += v >> 24;
            }
            float4 o;
            o.x = rsqrtf((float)(a0 < 1u ? 1u : a0));
            o.y = rsqrtf((float)(a1 < 1u ? 1u : a1));
            o.z = rsqrtf((float)(a2 < 1u ? 1u : a2));
            o.w = rsqrtf((float)(a3 < 1u ? 1u : a3));
            ((float4*)on)[tt] = o;
        }
    }
}

// ---- F3: gemm1 (B in registers from global; blocks 0..781) || scat2 (782..977) ----
__global__ __launch_bounds__(256, 4) void k_fuse3(
        const float* __restrict__ x, const float* __restrict__ on,
        const unsigned* __restrict__ Wt1, unsigned short* __restrict__ hb,
        const int* __restrict__ tmp_s, const int* __restrict__ tmp_d,
        const unsigned* __restrict__ base,
        unsigned* __restrict__ row_ptr, float* __restrict__ inn,
        int* __restrict__ csr) {
    __shared__ char smem[16384] __attribute__((aligned(16)));
    int tid = threadIdx.x;
    if (blockIdx.x < NTILES) {
        // GEMM1 (MFMA f16): quarter wv of f16((x*on)@W1) -> hb + wv*NPAD*32
        uint4* lA4 = (uint4*)smem;            // 16 KB: A only
        unsigned* lA = (unsigned*)lA4;
        int m0 = blockIdx.x * 64;

        const float2* x2 = (const float2*)x;
        for (int i = tid; i < 64 * 64; i += 256) {
            int m = i >> 6, kp = i & 63;
            int gm = m0 + m;
            float2 v = {0.f, 0.f}; float sc = 0.f;
            if (gm < N_NODES) { v = x2[(size_t)gm * 64 + kp]; sc = on[gm]; }
            lA[(m * 64 + kp) ^ ((m & 7) << 2)] = f16rn(v.x * sc) | (f16rn(v.y * sc) << 16);
        }

        int lane = tid & 63, wv = tid >> 6;
        int lm = lane & 15, lg = lane >> 4;
        int ncol0 = wv * 32;
        unsigned short* tabq = hb + (size_t)wv * NPAD * 32;

        // B fragments straight from global (L2-hot, shared by all blocks)
        const uint4* W4 = (const uint4*)Wt1;   // [128 rows][16 kq]
        uint4 breg[2][4];
        #pragma unroll
        for (int nt = 0; nt < 2; ++nt)
            #pragma unroll
            for (int ks = 0; ks < 4; ++ks)
                breg[nt][ks] = W4[(size_t)(ncol0 + nt * 16 + lm) * 16 + ks * 4 + lg];

        __syncthreads();

        f32x4 acc[4][2];
        #pragma unroll
        for (int a = 0; a < 4; ++a)
            #pragma unroll
            for (int b = 0; b < 2; ++b) acc[a][b] = f32x4{0.f, 0.f, 0.f, 0.f};

        #pragma unroll
        for (int ks = 0; ks < 4; ++ks) {
            f16x8 af[4];
            #pragma unroll
            for (int mt = 0; mt < 4; ++mt) {
                int row = mt * 16 + lm;
                af[mt] = __builtin_bit_cast(f16x8, lA4[(row * 16 + ks * 4 + lg) ^ (row & 7)]);
            }
            #pragma unroll
            for (int mt = 0; mt < 4; ++mt)
                #pragma unroll
                for (int nt = 0; nt < 2; ++nt)
                    acc[mt][nt] = __builtin_amdgcn_mfma_f32_16x16x32_f16(
                        af[mt], __builtin_bit_cast(f16x8, breg[nt][ks]), acc[mt][nt], 0, 0, 0);
        }
        #pragma unroll
        for (int mt = 0; mt < 4; ++mt)
            #pragma unroll
            for (int r = 0; r < 4; ++r) {
                int row = m0 + mt * 16 + lg * 4 + r;   // D: col=lane&15, row=(lane>>4)*4+reg
                #pragma unroll
                for (int nt = 0; nt < 2; ++nt) {
                    int lcol = nt * 16 + lm;
                    tabq[(size_t)row * 32 + lcol] = (unsigned short)f16rn(acc[mt][nt][r]);
                }
            }
    } else {
        // scat2: fine scatter within coarse bucket; emits row_ptr, inn, csr
        unsigned* hist = (unsigned*)smem;
        unsigned* cur  = hist + 256;
        unsigned* s    = cur + 256;
        int c = blockIdx.x - NTILES, t = tid;
        unsigned beg = base[c], end = base[c + 1];
        hist[t] = 0;
        __syncthreads();
        for (unsigned i = beg + t; i < end; i += 256)
            atomicAdd(&hist[(unsigned)tmp_d[i] & 255u], 1u);
        __syncthreads();
        unsigned v = hist[t];
        s[t] = v; __syncthreads();
        for (int o = 1; o < 256; o <<= 1) {
            unsigned u = (t >= o) ? s[t - o] : 0u;
            __syncthreads(); s[t] += u; __syncthreads();
        }
        unsigned excl = s[t] - v;
        int node = c * 256 + t;
        if (node < N_NODES) {
            row_ptr[node] = beg + excl;
            inn[node] = rsqrtf((float)(v < 1u ? 1u : v));
        }
        cur[t] = beg + excl;
        __syncthreads();
        for (unsigned i = beg + t; i < end; i += 256) {
            int d = tmp_d[i], sv = tmp_s[i];
            unsigned p = atomicAdd(&cur[(unsigned)d & 255u], 1u);
            csr[p] = sv;
        }
    }
}

// ---- GEMM2 (MFMA f16): 2 half tables h2b + (wv>>1)*NPAD*32 ----
__global__ __launch_bounds__(256, 2) void gemm2_mfma(
        const unsigned* __restrict__ h1b, const unsigned* __restrict__ Wt2,
        unsigned short* __restrict__ h2b) {
    __shared__ uint4 lA4[64 * 16];
    __shared__ uint4 lB4[64 * 16];
    unsigned* lA = (unsigned*)lA4;
    unsigned* lB = (unsigned*)lB4;
    int tid = threadIdx.x;
    int m0 = blockIdx.x * 64;

    for (int i = tid; i < 64 * 64; i += 256) {
        int n = i >> 6, kp = i & 63;
        lB[(n * 64 + kp) ^ ((n & 7) << 2)] = Wt2[i];
    }
    for (int i = tid; i < 64 * 64; i += 256) {
        int m = i >> 6, kp = i & 63;
        int gm = m0 + m;
        lA[(m * 64 + kp) ^ ((m & 7) << 2)] = (gm < N_NODES) ? h1b[(size_t)gm * 64 + kp] : 0u;
    }
    __syncthreads();

    int lane = tid & 63, wv = tid >> 6;
    int lm = lane & 15, lg = lane >> 4;
    int ncol0 = wv * 16;
    unsigned short* tabh = h2b + (size_t)(wv >> 1) * NPAD * 32;
    int lcol = (wv & 1) * 16 + lm;

    f32x4 acc[4];
    #pragma unroll
    for (int a = 0; a < 4; ++a) acc[a] = f32x4{0.f, 0.f, 0.f, 0.f};

    #pragma unroll
    for (int ks = 0; ks < 4; ++ks) {
        int brow = ncol0 + lm;
        f16x8 bfr = __builtin_bit_cast(f16x8, lB4[(brow * 16 + ks * 4 + lg) ^ (brow & 7)]);
        #pragma unroll
        for (int mt = 0; mt < 4; ++mt) {
            int row = mt * 16 + lm;
            f16x8 af = __builtin_bit_cast(f16x8, lA4[(row * 16 + ks * 4 + lg) ^ (row & 7)]);
            acc[mt] = __builtin_amdgcn_mfma_f32_16x16x32_f16(af, bfr, acc[mt], 0, 0, 0);
        }
    }
    #pragma unroll
    for (int mt = 0; mt < 4; ++mt)
        #pragma unroll
        for (int r = 0; r < 4; ++r) {
            int row = m0 + mt * 16 + lg * 4 + r;
            tabh[(size_t)row * 32 + lcol] = (unsigned short)f16rn(acc[mt][r]);
        }
}

// ---- agg1: 4 feature-quarter phases; direct csr loads (no bpermute), 16 gathers in flight ----
__global__ __launch_bounds__(256, 4) void k_agg1(
        const unsigned short* __restrict__ hb, const int* __restrict__ csr,
        const unsigned* __restrict__ row_ptr,
        const float* __restrict__ inn, const float* __restrict__ b1,
        const float* __restrict__ on, unsigned* __restrict__ h1b) {
    int qr = blockIdx.x / AGG_BPP;
    int bp = blockIdx.x % AGG_BPP;
    int tid = threadIdx.x;
    int lane = tid & 63;
    int l16 = lane & 15;
    int node_sub = lane >> 4;
    int w = l16 & 3;        // uint4 word within 64B row
    int slot = l16 >> 2;    // 0..3 edge sub-slot
    int n = bp * 16 + (tid >> 6) * 4 + node_sub;
    unsigned beg = row_ptr[n], end = row_ptr[n + 1];
    int m = (int)(end - beg);
    const uint4* tab = (const uint4*)(hb + (size_t)qr * NPAD * 32);
    f16x2 s0 = u2h(0), s1 = u2h(0), s2 = u2h(0), s3 = u2h(0);
    for (int jb = 0; jb < m; jb += 64) {
        unsigned idx[16];
        #pragma unroll
        for (int k = 0; k < 16; ++k) {
            unsigned e = beg + jb + 4 * k + slot;   // 4 lanes (w=0..3) share this address
            idx[k] = (e < end) ? (unsigned)csr[e] : (unsigned)DUMMY;
        }
        uint4 v[16];
        #pragma unroll
        for (int k = 0; k < 16; ++k)
            v[k] = tab[(size_t)idx[k] * 4 + w];
        #pragma unroll
        for (int k = 0; k < 16; ++k) {
            s0 += u2h(v[k].x); s1 += u2h(v[k].y);
            s2 += u2h(v[k].z); s3 += u2h(v[k].w);
        }
    }
    s0 = pk_xor_add(s0, 4); s1 = pk_xor_add(s1, 4);
    s2 = pk_xor_add(s2, 4); s3 = pk_xor_add(s3, 4);
    s0 = pk_xor_add(s0, 8); s1 = pk_xor_add(s1, 8);
    s2 = pk_xor_add(s2, 8); s3 = pk_xor_add(s3, 8);
    if (slot == 0) {
        float sc = inn[n], osc = on[n];
        float4 ba = ((const float4*)b1)[qr * 8 + w * 2];
        float4 bb = ((const float4*)b1)[qr * 8 + w * 2 + 1];
        float f0 = fmaxf((float)s0[0] * sc + ba.x, 0.f) * osc;
        float f1 = fmaxf((float)s0[1] * sc + ba.y, 0.f) * osc;
        float f2 = fmaxf((float)s1[0] * sc + ba.z, 0.f) * osc;
        float f3 = fmaxf((float)s1[1] * sc + ba.w, 0.f) * osc;
        float f4 = fmaxf((float)s2[0] * sc + bb.x, 0.f) * osc;
        float f5 = fmaxf((float)s2[1] * sc + bb.y, 0.f) * osc;
        float f6 = fmaxf((float)s3[0] * sc + bb.z, 0.f) * osc;
        float f7 = fmaxf((float)s3[1] * sc + bb.w, 0.f) * osc;
        uint4 o;
        o.x = f16rn(f0) | (f16rn(f1) << 16);
        o.y = f16rn(f2) | (f16rn(f3) << 16);
        o.z = f16rn(f4) | (f16rn(f5) << 16);
        o.w = f16rn(f6) | (f16rn(f7) << 16);
        ((uint4*)h1b)[(size_t)n * 16 + qr * 4 + w] = o;
    }
}

// ---- agg2: 2 feature-half phases; direct csr loads, 16 gathers in flight ----
__global__ __launch_bounds__(256, 4) void k_agg2(
        const unsigned short* __restrict__ h2b, const int* __restrict__ csr,
        const unsigned* __restrict__ row_ptr,
        const float* __restrict__ inn, const float* __restrict__ b2,
        float* __restrict__ out) {
    int hf = blockIdx.x / AGG_BPP;
    int bp = blockIdx.x % AGG_BPP;
    int tid = threadIdx.x;
    int lane = tid & 63;
    int l16 = lane & 15;
    int node_sub = lane >> 4;
    int w = l16 & 3;
    int slot = l16 >> 2;
    int n = bp * 16 + (tid >> 6) * 4 + node_sub;
    unsigned beg = row_ptr[n], end = row_ptr[n + 1];
    int m = (int)(end - beg);
    const uint4* tab = (const uint4*)(h2b + (size_t)hf * NPAD * 32);
    f16x2 s0 = u2h(0), s1 = u2h(0), s2 = u2h(0), s3 = u2h(0);
    for (int jb = 0; jb < m; jb += 64) {
        unsigned idx[16];
        #pragma unroll
        for (int k = 0; k < 16; ++k) {
            unsigned e = beg + jb + 4 * k + slot;
            idx[k] = (e < end) ? (unsigned)csr[e] : (unsigned)DUMMY;
        }
        uint4 v[16];
        #pragma unroll
        for (int k = 0; k < 16; ++k)
            v[k] = tab[(size_t)idx[k] * 4 + w];
        #pragma unroll
        for (int k = 0; k < 16; ++k) {
            s0 += u2h(v[k].x); s1 += u2h(v[k].y);
            s2 += u2h(v[k].z); s3 += u2h(v[k].w);
        }
    }
    s0 = pk_xor_add(s0, 4); s1 = pk_xor_add(s1, 4);
    s2 = pk_xor_add(s2, 4); s3 = pk_xor_add(s3, 4);
    s0 = pk_xor_add(s0, 8); s1 = pk_xor_add(s1, 8);
    s2 = pk_xor_add(s2, 8); s3 = pk_xor_add(s3, 8);
    if (slot == 0) {
        float sc = inn[n];
        float4 ba = ((const float4*)b2)[hf * 8 + w * 2];
        float4 bb = ((const float4*)b2)[hf * 8 + w * 2 + 1];
        float4 oA, oB;
        oA.x = (float)s0[0] * sc + ba.x; oA.y = (float)s0[1] * sc + ba.y;
        oA.z = (float)s1[0] * sc + ba.z; oA.w = (float)s1[1] * sc + ba.w;
        oB.x = (float)s2[0] * sc + bb.x; oB.y = (float)s2[1] * sc + bb.y;
        oB.z = (float)s3[0] * sc + bb.z; oB.w = (float)s3[1] * sc + bb.w;
        ((float4*)out)[(size_t)n * 16 + hf * 8 + w * 2]     = oA;
        ((float4*)out)[(size_t)n * 16 + hf * 8 + w * 2 + 1] = oB;
    }
}

extern "C" void kernel_launch(void* const* d_in, const int* in_sizes, int n_in,
                              void* d_out, int out_size, void* d_ws, size_t ws_size,
                              hipStream_t stream) {
    const float* x  = (const float*)d_in[0];
    const float* W1 = (const float*)d_in[1];
    const float* b1 = (const float*)d_in[2];
    const float* W2 = (const float*)d_in[3];
    const float* b2 = (const float*)d_in[4];
    const int*   src = (const int*)d_in[5];
    const int*   dst = (const int*)d_in[6];
    float* out = (float*)d_out;

    char* ws = (char*)d_ws;
    size_t off = 0;
    auto alloc = [&](size_t bytes) -> void* {
        void* p = ws + off;
        off += (bytes + 255) & ~(size_t)255;
        return p;
    };

    // All buffers DISJOINT — fused kernels run components concurrently.
    float*        on      = (float*)alloc((size_t)N_NODES * 4);
    float*        inn     = (float*)alloc((size_t)N_NODES * 4);
    unsigned int* row_ptr = (unsigned int*)alloc((size_t)(N_NODES + 1) * 4);
    unsigned int* base    = (unsigned int*)alloc((NCOARSE + 1) * 4);
    unsigned int* tot     = (unsigned int*)alloc(NCOARSE * 4);
    unsigned int* Wt1     = (unsigned int*)alloc(128 * 64 * 4);
    unsigned int* Wt2     = (unsigned int*)alloc(64 * 64 * 4);
    unsigned int* counts  = (unsigned int*)alloc((size_t)CBLK * NCOARSE * 4);
    unsigned int* woff    = (unsigned int*)alloc((size_t)CBLK * NCOARSE * 4);
    int*          csr     = (int*)alloc((size_t)N_EDGES * 4);
    int*          tmp_s   = (int*)alloc((size_t)N_EDGES * 4);
    int*          tmp_d   = (int*)alloc((size_t)N_EDGES * 4);
    unsigned int* partial = (unsigned int*)alloc((size_t)OPARTS * ONW * 4);       // 12.8 MB
    unsigned short* hb    = (unsigned short*)alloc((size_t)4 * NPAD * 32 * 2);    // 4 quarter tables
    unsigned int* h1b     = (unsigned int*)alloc((size_t)NPAD * 64 * 4);
    unsigned short* h2b   = (unsigned short*)alloc((size_t)2 * NPAD * 32 * 2);    // 2 half tables

    // 8 launches total
    k_fuse1<<<544, 256, 0, stream>>>(src, dst, W1, W2, counts, partial, Wt1, Wt2);
    k_scanA<<<NCOARSE, 256, 0, stream>>>(counts, woff, tot);
    k_scanB<<<1, 256, 0, stream>>>(tot, base, row_ptr);
    k_fuse2<<<256 + (ONW + 255) / 256, 256, 0, stream>>>(src, dst, base, woff, tmp_s, tmp_d, partial, on);
    k_fuse3<<<NTILES + NCOARSE, 256, 0, stream>>>(x, on, Wt1, hb, tmp_s, tmp_d, base, row_ptr, inn, csr);
    k_agg1<<<4 * AGG_BPP, 256, 0, stream>>>(hb, csr, row_ptr, inn, b1, on, h1b);
    gemm2_mfma<<<NTILES, 256, 0, stream>>>(h1b, Wt2, h2b);
    k_agg2<<<2 * AGG_BPP, 256, 0, stream>>>(h2b, csr, row_ptr, inn, b2, out);
}

// Round 17
// 152.595 us; speedup vs baseline: 1.0918x; 1.0918x over previous
//
#include <hip/hip_runtime.h>
#include <cstdint>

#define N_NODES 50000
#define N_EDGES 1600000
#define NPAD 50048                    // 782 tiles * 64
#define NTILES (NPAD / 64)            // 782
#define DUMMY 50000                   // zero row in padded tables

#define NCOARSE 196                   // ceil(50000/256)
#define CBLK 256                      // blocks in coarse pass
#define ECHUNK (N_EDGES / CBLK)       // 6250 edges per block

#define ONW 12500                     // 50000 nodes as u8-packed u32 words
#define OPARTS 256
#define OCH (N_EDGES / OPARTS)        // 6250 edges per part

#define AGG_BPP 3125                  // agg blocks per phase (16 nodes/block)

typedef __attribute__((ext_vector_type(8))) _Float16 f16x8;
typedef __attribute__((ext_vector_type(2))) _Float16 f16x2;
typedef __attribute__((ext_vector_type(4))) float f32x4;

// ---------------- helpers ----------------
__device__ __forceinline__ unsigned f16rn(float f) {
    _Float16 h = (_Float16)f;
    return (unsigned)__builtin_bit_cast(unsigned short, h);
}
__device__ __forceinline__ f16x2 u2h(unsigned u) { return __builtin_bit_cast(f16x2, u); }
__device__ __forceinline__ f16x2 pk_xor_add(f16x2 s, int d) {
    unsigned u = __builtin_bit_cast(unsigned, s);
    unsigned o = (unsigned)__shfl_xor((int)u, d);
    return s + __builtin_bit_cast(f16x2, o);           // v_pk_add_f16
}

// ---- F1: odp u8 (blocks 0..255) || hist (256..511) || wprep (512..543) ----
__global__ void k_fuse1(const int* __restrict__ src, const int* __restrict__ dst,
                        const float* __restrict__ W1, const float* __restrict__ W2,
                        unsigned* __restrict__ counts, unsigned* __restrict__ partial,
                        unsigned* __restrict__ Wt1, unsigned* __restrict__ Wt2) {
    __shared__ unsigned sm[ONW];      // 50 KB
    int b = blockIdx.x, tid = threadIdx.x;
    if (b < 256) {
        // outdeg partial histograms, 4x u8 packed per u32
        for (int i = tid; i < ONW; i += 256) sm[i] = 0;
        __syncthreads();
        int ebase = b * OCH;
        for (int i = tid; i < OCH; i += 256) {
            int sv = src[ebase + i];
            atomicAdd(&sm[sv >> 2], 1u << ((sv & 3) * 8));
        }
        __syncthreads();
        unsigned* outp = partial + (size_t)b * ONW;
        for (int i = tid; i < ONW; i += 256) outp[i] = sm[i];
    } else if (b < 512) {
        // coarse dst histogram
        int b2 = b - 256;
        for (int i = tid; i < NCOARSE; i += 256) sm[i] = 0;
        __syncthreads();
        int base = b2 * ECHUNK;
        for (int i = tid; i < ECHUNK; i += 256)
            atomicAdd(&sm[(unsigned)dst[base + i] >> 8], 1u);
        __syncthreads();
        for (int i = tid; i < NCOARSE; i += 256)
            counts[b2 * NCOARSE + i] = sm[i];
    } else {
        // W prep: Wt[n][kp] = packed fp16 (W[2kp][n], W[2kp+1][n])
        int t = (b - 512) * 256 + tid;
        if (t < 128 * 64) {
            int n = t >> 6, kp = t & 63;
            Wt1[t] = f16rn(W1[(2 * kp) * 128 + n]) | (f16rn(W1[(2 * kp + 1) * 128 + n]) << 16);
        }
        if (t < 64 * 64) {
            int n = t >> 6, kp = t & 63;
            Wt2[t] = f16rn(W2[(2 * kp) * 64 + n]) | (f16rn(W2[(2 * kp + 1) * 64 + n]) << 16);
        }
    }
}

// ---- scanA: scan block-counts within each coarse bucket ----
__global__ void k_scanA(const unsigned* __restrict__ counts, unsigned* __restrict__ woff,
                        unsigned* __restrict__ tot) {
    __shared__ unsigned s[256];
    int c = blockIdx.x, t = threadIdx.x;
    unsigned v = counts[t * NCOARSE + c];
    s[t] = v; __syncthreads();
    for (int o = 1; o < 256; o <<= 1) {
        unsigned u = (t >= o) ? s[t - o] : 0u;
        __syncthreads(); s[t] += u; __syncthreads();
    }
    woff[t * NCOARSE + c] = s[t] - v;
    if (t == 255) tot[c] = s[255];
}

// ---- scanB: scan bucket totals -> base[], row_ptr tail ----
__global__ void k_scanB(const unsigned* __restrict__ tot, unsigned* __restrict__ base,
                        unsigned* __restrict__ row_ptr) {
    __shared__ unsigned s[256];
    int t = threadIdx.x;
    unsigned v = (t < NCOARSE) ? tot[t] : 0u;
    s[t] = v; __syncthreads();
    for (int o = 1; o < 256; o <<= 1) {
        unsigned u = (t >= o) ? s[t - o] : 0u;
        __syncthreads(); s[t] += u; __syncthreads();
    }
    if (t < NCOARSE) base[t] = s[t] - v;
    if (t == NCOARSE - 1) base[NCOARSE] = s[t];   // == N_EDGES
    if (t == 0) row_ptr[N_NODES] = N_EDGES;
}

// ---- F2: scat1 (blocks 0..255) || on-reduce (256..304) ----
__global__ void k_fuse2(const int* __restrict__ src, const int* __restrict__ dst,
                        const unsigned* __restrict__ base, const unsigned* __restrict__ woff,
                        int* __restrict__ tmp_s, int* __restrict__ tmp_d,
                        const unsigned* __restrict__ partial, float* __restrict__ on) {
    __shared__ unsigned cur[NCOARSE];
    int b = blockIdx.x, t = threadIdx.x;
    if (b < 256) {
        for (int i = t; i < NCOARSE; i += 256) cur[i] = base[i] + woff[b * NCOARSE + i];
        __syncthreads();
        int ebase = b * ECHUNK;
        for (int i = t; i < ECHUNK; i += 256) {
            int d = dst[ebase + i], sv = src[ebase + i];
            unsigned p = atomicAdd(&cur[(unsigned)d >> 8], 1u);
            tmp_d[p] = d; tmp_s[p] = sv;
        }
    } else {
        int tt = (b - 256) * 256 + t;   // packed word index
        if (tt < ONW) {
            const unsigned* p = partial + tt;
            unsigned a0 = 0, a1 = 0, a2 = 0, a3 = 0;
            for (int q = 0; q < OPARTS; ++q) {
                unsigned v = p[(size_t)q * ONW];
                a0 += v & 255u; a1 += (v >> 8) & 255u;
                a2 += (v >> 16) & 255u; a3 += v >> 24;
            }
            float4 o;
            o.x = rsqrtf((float)(a0 < 1u ? 1u : a0));
            o.y = rsqrtf((float)(a1 < 1u ? 1u : a1));
            o.z = rsqrtf((float)(a2 < 1u ? 1u : a2));
            o.w = rsqrtf((float)(a3 < 1u ? 1u : a3));
            ((float4*)on)[tt] = o;
        }
    }
}

// ---- F3: gemm1 (B in registers from global; blocks 0..781) || scat2 (782..977) ----
__global__ __launch_bounds__(256, 4) void k_fuse3(
        const float* __restrict__ x, const float* __restrict__ on,
        const unsigned* __restrict__ Wt1, unsigned short* __restrict__ hb,
        const int* __restrict__ tmp_s, const int* __restrict__ tmp_d,
        const unsigned* __restrict__ base,
        unsigned* __restrict__ row_ptr, float* __restrict__ inn,
        int* __restrict__ csr) {
    __shared__ char smem[16384] __attribute__((aligned(16)));
    int tid = threadIdx.x;
    if (blockIdx.x < NTILES) {
        // GEMM1 (MFMA f16): quarter wv of f16((x*on)@W1) -> hb + wv*NPAD*32
        uint4* lA4 = (uint4*)smem;            // 16 KB: A only
        unsigned* lA = (unsigned*)lA4;
        int m0 = blockIdx.x * 64;

        const float2* x2 = (const float2*)x;
        for (int i = tid; i < 64 * 64; i += 256) {
            int m = i >> 6, kp = i & 63;
            int gm = m0 + m;
            float2 v = {0.f, 0.f}; float sc = 0.f;
            if (gm < N_NODES) { v = x2[(size_t)gm * 64 + kp]; sc = on[gm]; }
            lA[(m * 64 + kp) ^ ((m & 7) << 2)] = f16rn(v.x * sc) | (f16rn(v.y * sc) << 16);
        }

        int lane = tid & 63, wv = tid >> 6;
        int lm = lane & 15, lg = lane >> 4;
        int ncol0 = wv * 32;
        unsigned short* tabq = hb + (size_t)wv * NPAD * 32;

        // B fragments straight from global (L2-hot, shared by all blocks)
        const uint4* W4 = (const uint4*)Wt1;   // [128 rows][16 kq]
        uint4 breg[2][4];
        #pragma unroll
        for (int nt = 0; nt < 2; ++nt)
            #pragma unroll
            for (int ks = 0; ks < 4; ++ks)
                breg[nt][ks] = W4[(size_t)(ncol0 + nt * 16 + lm) * 16 + ks * 4 + lg];

        __syncthreads();

        f32x4 acc[4][2];
        #pragma unroll
        for (int a = 0; a < 4; ++a)
            #pragma unroll
            for (int b = 0; b < 2; ++b) acc[a][b] = f32x4{0.f, 0.f, 0.f, 0.f};

        #pragma unroll
        for (int ks = 0; ks < 4; ++ks) {
            f16x8 af[4];
            #pragma unroll
            for (int mt = 0; mt < 4; ++mt) {
                int row = mt * 16 + lm;
                af[mt] = __builtin_bit_cast(f16x8, lA4[(row * 16 + ks * 4 + lg) ^ (row & 7)]);
            }
            #pragma unroll
            for (int mt = 0; mt < 4; ++mt)
                #pragma unroll
                for (int nt = 0; nt < 2; ++nt)
                    acc[mt][nt] = __builtin_amdgcn_mfma_f32_16x16x32_f16(
                        af[mt], __builtin_bit_cast(f16x8, breg[nt][ks]), acc[mt][nt], 0, 0, 0);
        }
        #pragma unroll
        for (int mt = 0; mt < 4; ++mt)
            #pragma unroll
            for (int r = 0; r < 4; ++r) {
                int row = m0 + mt * 16 + lg * 4 + r;   // D: col=lane&15, row=(lane>>4)*4+reg
                #pragma unroll
                for (int nt = 0; nt < 2; ++nt) {
                    int lcol = nt * 16 + lm;
                    tabq[(size_t)row * 32 + lcol] = (unsigned short)f16rn(acc[mt][nt][r]);
                }
            }
    } else {
        // scat2: fine scatter within coarse bucket; emits row_ptr, inn, csr
        unsigned* hist = (unsigned*)smem;
        unsigned* cur  = hist + 256;
        unsigned* s    = cur + 256;
        int c = blockIdx.x - NTILES, t = tid;
        unsigned beg = base[c], end = base[c + 1];
        hist[t] = 0;
        __syncthreads();
        for (unsigned i = beg + t; i < end; i += 256)
            atomicAdd(&hist[(unsigned)tmp_d[i] & 255u], 1u);
        __syncthreads();
        unsigned v = hist[t];
        s[t] = v; __syncthreads();
        for (int o = 1; o < 256; o <<= 1) {
            unsigned u = (t >= o) ? s[t - o] : 0u;
            __syncthreads(); s[t] += u; __syncthreads();
        }
        unsigned excl = s[t] - v;
        int node = c * 256 + t;
        if (node < N_NODES) {
            row_ptr[node] = beg + excl;
            inn[node] = rsqrtf((float)(v < 1u ? 1u : v));
        }
        cur[t] = beg + excl;
        __syncthreads();
        for (unsigned i = beg + t; i < end; i += 256) {
            int d = tmp_d[i], sv = tmp_s[i];
            unsigned p = atomicAdd(&cur[(unsigned)d & 255u], 1u);
            csr[p] = sv;
        }
    }
}

// ---- GEMM2 (MFMA f16): 2 half tables h2b + (wv>>1)*NPAD*32 ----
__global__ __launch_bounds__(256, 2) void gemm2_mfma(
        const unsigned* __restrict__ h1b, const unsigned* __restrict__ Wt2,
        unsigned short* __restrict__ h2b) {
    __shared__ uint4 lA4[64 * 16];
    __shared__ uint4 lB4[64 * 16];
    unsigned* lA = (unsigned*)lA4;
    unsigned* lB = (unsigned*)lB4;
    int tid = threadIdx.x;
    int m0 = blockIdx.x * 64;

    for (int i = tid; i < 64 * 64; i += 256) {
        int n = i >> 6, kp = i & 63;
        lB[(n * 64 + kp) ^ ((n & 7) << 2)] = Wt2[i];
    }
    for (int i = tid; i < 64 * 64; i += 256) {
        int m = i >> 6, kp = i & 63;
        int gm = m0 + m;
        lA[(m * 64 + kp) ^ ((m & 7) << 2)] = (gm < N_NODES) ? h1b[(size_t)gm * 64 + kp] : 0u;
    }
    __syncthreads();

    int lane = tid & 63, wv = tid >> 6;
    int lm = lane & 15, lg = lane >> 4;
    int ncol0 = wv * 16;
    unsigned short* tabh = h2b + (size_t)(wv >> 1) * NPAD * 32;
    int lcol = (wv & 1) * 16 + lm;

    f32x4 acc[4];
    #pragma unroll
    for (int a = 0; a < 4; ++a) acc[a] = f32x4{0.f, 0.f, 0.f, 0.f};

    #pragma unroll
    for (int ks = 0; ks < 4; ++ks) {
        int brow = ncol0 + lm;
        f16x8 bfr = __builtin_bit_cast(f16x8, lB4[(brow * 16 + ks * 4 + lg) ^ (brow & 7)]);
        #pragma unroll
        for (int mt = 0; mt < 4; ++mt) {
            int row = mt * 16 + lm;
            f16x8 af = __builtin_bit_cast(f16x8, lA4[(row * 16 + ks * 4 + lg) ^ (row & 7)]);
            acc[mt] = __builtin_amdgcn_mfma_f32_16x16x32_f16(af, bfr, acc[mt], 0, 0, 0);
        }
    }
    #pragma unroll
    for (int mt = 0; mt < 4; ++mt)
        #pragma unroll
        for (int r = 0; r < 4; ++r) {
            int row = m0 + mt * 16 + lg * 4 + r;
            tabh[(size_t)row * 32 + lcol] = (unsigned short)f16rn(acc[mt][r]);
        }
}

// ---- agg1: 4 feature-quarter phases; 64 edges/iter, shfl-broadcast indices ----
__global__ __launch_bounds__(256) void k_agg1(
        const unsigned short* __restrict__ hb, const int* __restrict__ csr,
        const unsigned* __restrict__ row_ptr,
        const float* __restrict__ inn, const float* __restrict__ b1,
        const float* __restrict__ on, unsigned* __restrict__ h1b) {
    int qr = blockIdx.x / AGG_BPP;
    int bp = blockIdx.x % AGG_BPP;
    int tid = threadIdx.x;
    int lane = tid & 63;
    int l16 = lane & 15;
    int node_sub = lane >> 4;
    int w = l16 & 3;
    int slot = l16 >> 2;
    int n = bp * 16 + (tid >> 6) * 4 + node_sub;
    unsigned beg = row_ptr[n], end = row_ptr[n + 1];
    int m = (int)(end - beg);
    const uint4* tab = (const uint4*)(hb + (size_t)qr * NPAD * 32);
    f16x2 s0 = u2h(0), s1 = u2h(0), s2 = u2h(0), s3 = u2h(0);
    for (int jb = 0; jb < m; jb += 64) {
        unsigned e0 = beg + jb + l16;
        int r0 = (e0      < end) ? csr[e0]      : DUMMY;
        int r1 = (e0 + 16 < end) ? csr[e0 + 16] : DUMMY;
        int r2 = (e0 + 32 < end) ? csr[e0 + 32] : DUMMY;
        int r3 = (e0 + 48 < end) ? csr[e0 + 48] : DUMMY;
        uint4 v[16];
        #pragma unroll
        for (int k = 0; k < 16; ++k) {
            int sl = 4 * k + slot;                 // 0..63
            int which = k >> 2;                    // 16-edge group
            int rr = which == 0 ? r0 : which == 1 ? r1 : which == 2 ? r2 : r3;
            int srcl = node_sub * 16 + (sl & 15);
            unsigned idx = (unsigned)__shfl(rr, srcl);
            v[k] = tab[(size_t)idx * 4 + w];
        }
        #pragma unroll
        for (int k = 0; k < 16; ++k) {
            s0 += u2h(v[k].x); s1 += u2h(v[k].y);
            s2 += u2h(v[k].z); s3 += u2h(v[k].w);
        }
    }
    s0 = pk_xor_add(s0, 4); s1 = pk_xor_add(s1, 4);
    s2 = pk_xor_add(s2, 4); s3 = pk_xor_add(s3, 4);
    s0 = pk_xor_add(s0, 8); s1 = pk_xor_add(s1, 8);
    s2 = pk_xor_add(s2, 8); s3 = pk_xor_add(s3, 8);
    if (slot == 0) {
        float sc = inn[n], osc = on[n];
        float4 ba = ((const float4*)b1)[qr * 8 + w * 2];
        float4 bb = ((const float4*)b1)[qr * 8 + w * 2 + 1];
        float f0 = fmaxf((float)s0[0] * sc + ba.x, 0.f) * osc;
        float f1 = fmaxf((float)s0[1] * sc + ba.y, 0.f) * osc;
        float f2 = fmaxf((float)s1[0] * sc + ba.z, 0.f) * osc;
        float f3 = fmaxf((float)s1[1] * sc + ba.w, 0.f) * osc;
        float f4 = fmaxf((float)s2[0] * sc + bb.x, 0.f) * osc;
        float f5 = fmaxf((float)s2[1] * sc + bb.y, 0.f) * osc;
        float f6 = fmaxf((float)s3[0] * sc + bb.z, 0.f) * osc;
        float f7 = fmaxf((float)s3[1] * sc + bb.w, 0.f) * osc;
        uint4 o;
        o.x = f16rn(f0) | (f16rn(f1) << 16);
        o.y = f16rn(f2) | (f16rn(f3) << 16);
        o.z = f16rn(f4) | (f16rn(f5) << 16);
        o.w = f16rn(f6) | (f16rn(f7) << 16);
        ((uint4*)h1b)[(size_t)n * 16 + qr * 4 + w] = o;
    }
}

// ---- agg2: 2 feature-half phases; 64 edges/iter, shfl-broadcast indices ----
__global__ __launch_bounds__(256) void k_agg2(
        const unsigned short* __restrict__ h2b, const int* __restrict__ csr,
        const unsigned* __restrict__ row_ptr,
        const float* __restrict__ inn, const float* __restrict__ b2,
        float* __restrict__ out) {
    int hf = blockIdx.x / AGG_BPP;
    int bp = blockIdx.x % AGG_BPP;
    int tid = threadIdx.x;
    int lane = tid & 63;
    int l16 = lane & 15;
    int node_sub = lane >> 4;
    int w = l16 & 3;
    int slot = l16 >> 2;
    int n = bp * 16 + (tid >> 6) * 4 + node_sub;
    unsigned beg = row_ptr[n], end = row_ptr[n + 1];
    int m = (int)(end - beg);
    const uint4* tab = (const uint4*)(h2b + (size_t)hf * NPAD * 32);
    f16x2 s0 = u2h(0), s1 = u2h(0), s2 = u2h(0), s3 = u2h(0);
    for (int jb = 0; jb < m; jb += 64) {
        unsigned e0 = beg + jb + l16;
        int r0 = (e0      < end) ? csr[e0]      : DUMMY;
        int r1 = (e0 + 16 < end) ? csr[e0 + 16] : DUMMY;
        int r2 = (e0 + 32 < end) ? csr[e0 + 32] : DUMMY;
        int r3 = (e0 + 48 < end) ? csr[e0 + 48] : DUMMY;
        uint4 v[16];
        #pragma unroll
        for (int k = 0; k < 16; ++k) {
            int sl = 4 * k + slot;
            int which = k >> 2;
            int rr = which == 0 ? r0 : which == 1 ? r1 : which == 2 ? r2 : r3;
            int srcl = node_sub * 16 + (sl & 15);
            unsigned idx = (unsigned)__shfl(rr, srcl);
            v[k] = tab[(size_t)idx * 4 + w];
        }
        #pragma unroll
        for (int k = 0; k < 16; ++k) {
            s0 += u2h(v[k].x); s1 += u2h(v[k].y);
            s2 += u2h(v[k].z); s3 += u2h(v[k].w);
        }
    }
    s0 = pk_xor_add(s0, 4); s1 = pk_xor_add(s1, 4);
    s2 = pk_xor_add(s2, 4); s3 = pk_xor_add(s3, 4);
    s0 = pk_xor_add(s0, 8); s1 = pk_xor_add(s1, 8);
    s2 = pk_xor_add(s2, 8); s3 = pk_xor_add(s3, 8);
    if (slot == 0) {
        float sc = inn[n];
        float4 ba = ((const float4*)b2)[hf * 8 + w * 2];
        float4 bb = ((const float4*)b2)[hf * 8 + w * 2 + 1];
        float4 oA, oB;
        oA.x = (float)s0[0] * sc + ba.x; oA.y = (float)s0[1] * sc + ba.y;
        oA.z = (float)s1[0] * sc + ba.z; oA.w = (float)s1[1] * sc + ba.w;
        oB.x = (float)s2[0] * sc + bb.x; oB.y = (float)s2[1] * sc + bb.y;
        oB.z = (float)s3[0] * sc + bb.z; oB.w = (float)s3[1] * sc + bb.w;
        ((float4*)out)[(size_t)n * 16 + hf * 8 + w * 2]     = oA;
        ((float4*)out)[(size_t)n * 16 + hf * 8 + w * 2 + 1] = oB;
    }
}

extern "C" void kernel_launch(void* const* d_in, const int* in_sizes, int n_in,
                              void* d_out, int out_size, void* d_ws, size_t ws_size,
                              hipStream_t stream) {
    const float* x  = (const float*)d_in[0];
    const float* W1 = (const float*)d_in[1];
    const float* b1 = (const float*)d_in[2];
    const float* W2 = (const float*)d_in[3];
    const float* b2 = (const float*)d_in[4];
    const int*   src = (const int*)d_in[5];
    const int*   dst = (const int*)d_in[6];
    float* out = (float*)d_out;

    char* ws = (char*)d_ws;
    size_t off = 0;
    auto alloc = [&](size_t bytes) -> void* {
        void* p = ws + off;
        off += (bytes + 255) & ~(size_t)255;
        return p;
    };

    // All buffers DISJOINT — fused kernels run components concurrently.
    float*        on      = (float*)alloc((size_t)N_NODES * 4);
    float*        inn     = (float*)alloc((size_t)N_NODES * 4);
    unsigned int* row_ptr = (unsigned int*)alloc((size_t)(N_NODES + 1) * 4);
    unsigned int* base    = (unsigned int*)alloc((NCOARSE + 1) * 4);
    unsigned int* tot     = (unsigned int*)alloc(NCOARSE * 4);
    unsigned int* Wt1     = (unsigned int*)alloc(128 * 64 * 4);
    unsigned int* Wt2     = (unsigned int*)alloc(64 * 64 * 4);
    unsigned int* counts  = (unsigned int*)alloc((size_t)CBLK * NCOARSE * 4);
    unsigned int* woff    = (unsigned int*)alloc((size_t)CBLK * NCOARSE * 4);
    int*          csr     = (int*)alloc((size_t)N_EDGES * 4);
    int*          tmp_s   = (int*)alloc((size_t)N_EDGES * 4);
    int*          tmp_d   = (int*)alloc((size_t)N_EDGES * 4);
    unsigned int* partial = (unsigned int*)alloc((size_t)OPARTS * ONW * 4);       // 12.8 MB
    unsigned short* hb    = (unsigned short*)alloc((size_t)4 * NPAD * 32 * 2);    // 4 quarter tables
    unsigned int* h1b     = (unsigned int*)alloc((size_t)NPAD * 64 * 4);
    unsigned short* h2b   = (unsigned short*)alloc((size_t)2 * NPAD * 32 * 2);    // 2 half tables

    // 8 launches total
    k_fuse1<<<544, 256, 0, stream>>>(src, dst, W1, W2, counts, partial, Wt1, Wt2);
    k_scanA<<<NCOARSE, 256, 0, stream>>>(counts, woff, tot);
    k_scanB<<<1, 256, 0, stream>>>(tot, base, row_ptr);
    k_fuse2<<<256 + (ONW + 255) / 256, 256, 0, stream>>>(src, dst, base, woff, tmp_s, tmp_d, partial, on);
    k_fuse3<<<NTILES + NCOARSE, 256, 0, stream>>>(x, on, Wt1, hb, tmp_s, tmp_d, base, row_ptr, inn, csr);
    k_agg1<<<4 * AGG_BPP, 256, 0, stream>>>(hb, csr, row_ptr, inn, b1, on, h1b);
    gemm2_mfma<<<NTILES, 256, 0, stream>>>(h1b, Wt2, h2b);
    k_agg2<<<2 * AGG_BPP, 256, 0, stream>>>(h2b, csr, row_ptr, inn, b2, out);
}